// Round 3
// baseline (58.921 us; speedup 1.0000x reference)
//
#include <hip/hip_runtime.h>
#include <hip/hip_cooperative_groups.h>
#include <math.h>

namespace cg = cooperative_groups;

#define N_PTS 131072
#define UNITS 256
#define BLOCK 256
#define GRID  (N_PTS / BLOCK)   // 512 blocks, one thread per point

// Closed form: phi = exp(-0.5*s), s = (x-cx)^2 + (y-cy)^2
//   u_pred = sum phi*w
//   sh     = u + 2*lap(u) + biharm(u) = sum phi*w*(s^2 - 6s + 5)
//
// Let c = -0.5*log2(e):  exp(-0.5*s) = exp2(c*s).
//   c*s = tb + q,  tb = c*(x^2+y^2)  (per thread),
//   q = A*x + B*y + D,  A = -2c*cx, B = -2c*cy, D = c*(cx^2+cy^2)  (per center).
// Factor E0 = exp2(tb) out of both sums; express poly(s) in q:
//   s = q/c + r0, r0 = x^2+y^2
//   s^2-6s+5 = alpha*q^2 + beta*q + gamma
//   alpha = 1/c^2 (global), beta = (2*r0-6)/c, gamma = r0^2-6*r0+5 (per thread)
// Inner loop: 7 VALU + 1 exp2 per center.

__global__ __launch_bounds__(BLOCK) void rbf_pinn_coop(
    const float* __restrict__ x, const float* __restrict__ y,
    const float* __restrict__ u, const float* __restrict__ centers,
    const float* __restrict__ W, const float* __restrict__ eps,
    const float* __restrict__ delta, const float* __restrict__ gam,
    const int* __restrict__ iters, float* __restrict__ partial,
    float* __restrict__ out)
{
    constexpr double LOG2E = 1.4426950408889634073599;
    constexpr float  cF    = (float)(-0.5 * LOG2E);            // c
    constexpr float  alpha = (float)(1.0 / (0.25 * LOG2E * LOG2E)); // 1/c^2
    constexpr float  m2c   = (float)(2.0 / (-0.5 * LOG2E));    // 2/c
    constexpr float  m6c   = (float)(-6.0 / (-0.5 * LOG2E));   // -6/c

    __shared__ float4 s_coef[UNITS];
    const int t = threadIdx.x;

    // Per-block prologue: pack per-center coefficients (UNITS == BLOCK).
    {
        const float cx = centers[2 * t + 0];
        const float cy = centers[2 * t + 1];
        const float w  = W[t];
        const float A  = -2.f * cF * cx;
        const float B  = -2.f * cF * cy;
        const float D  = cF * fmaf(cx, cx, cy * cy);
        s_coef[t] = make_float4(A, B, D, w);
    }
    __syncthreads();

    const int i = blockIdx.x * BLOCK + t;
    const float xi = x[i];
    const float yi = y[i];
    const float ui = u[i];

    const float r0   = fmaf(xi, xi, yi * yi);
    const float E0   = __builtin_amdgcn_exp2f(cF * r0);
    const float beta = fmaf(m2c, r0, m6c);
    const float gmma = fmaf(r0, r0 - 6.f, 5.f);

    float up = 0.f;
    float sh = 0.f;

    #pragma unroll 8
    for (int j = 0; j < UNITS; ++j) {
        const float4 cf = s_coef[j];                       // ds_read_b128 broadcast
        const float q    = fmaf(cf.x, xi, fmaf(cf.y, yi, cf.z));
        const float e    = __builtin_amdgcn_exp2f(q);
        const float p1   = fmaf(alpha, q, beta);
        const float poly = fmaf(q, p1, gmma);
        const float ew   = e * cf.w;
        up += ew;
        sh = fmaf(ew, poly, sh);
    }
    up *= E0;
    sh *= E0;

    const int   it   = iters[0];
    const float epsv = eps[0];
    const float dl   = delta[0];
    const float gm   = gam[0];
    float c2, c3;
    if (it < 10000)      { c2 = 0.0f; c3 = 0.0f; }
    else if (it < 20000) { c2 = 0.3f; c3 = 0.0f; }
    else if (it < 30000) { c2 = 0.7f; c3 = 0.3f; }
    else                 { c2 = 1.0f; c3 = 1.0f; }

    const float up2 = up * up;
    const float res = epsv * up - c2 * dl * up2 - c3 * gm * up2 * up - sh;
    const float d   = up - ui;

    float a0 = d * d;
    float a1 = ui * ui;
    float a2 = res * res;

    #pragma unroll
    for (int o = 32; o > 0; o >>= 1) {
        a0 += __shfl_down(a0, o);
        a1 += __shfl_down(a1, o);
        a2 += __shfl_down(a2, o);
    }
    __shared__ float s_r[3][BLOCK / 64];
    const int lane = t & 63;
    const int wv   = t >> 6;
    if (lane == 0) { s_r[0][wv] = a0; s_r[1][wv] = a1; s_r[2][wv] = a2; }
    __syncthreads();
    if (t == 0) {
        float r0s = 0.f, r1s = 0.f, r2s = 0.f;
        #pragma unroll
        for (int w2 = 0; w2 < BLOCK / 64; ++w2) {
            r0s += s_r[0][w2]; r1s += s_r[1][w2]; r2s += s_r[2][w2];
        }
        partial[0 * GRID + blockIdx.x] = r0s;
        partial[1 * GRID + blockIdx.x] = r1s;
        partial[2 * GRID + blockIdx.x] = r2s;
    }

    cg::this_grid().sync();
    if (blockIdx.x != 0) return;

    // Block 0: final reduction over 512 partials (fixed order, deterministic).
    float b0 = 0.f, b1 = 0.f, b2 = 0.f;
    #pragma unroll
    for (int k = t; k < GRID; k += BLOCK) {
        b0 += partial[0 * GRID + k];
        b1 += partial[1 * GRID + k];
        b2 += partial[2 * GRID + k];
    }
    #pragma unroll
    for (int o = 32; o > 0; o >>= 1) {
        b0 += __shfl_down(b0, o);
        b1 += __shfl_down(b1, o);
        b2 += __shfl_down(b2, o);
    }
    if (lane == 0) { s_r[0][wv] = b0; s_r[1][wv] = b1; s_r[2][wv] = b2; }
    __syncthreads();
    if (t == 0) {
        float S0 = 0.f, S1 = 0.f, S2 = 0.f;
        #pragma unroll
        for (int w2 = 0; w2 < BLOCK / 64; ++w2) {
            S0 += s_r[0][w2]; S1 += s_r[1][w2]; S2 += s_r[2][w2];
        }
        const float loss_u   = S0 / S1;
        const float loss_pde = S2 / (float)N_PTS;
        float cw;
        if (it < 10000)      cw = 0.1f;
        else if (it < 20000) cw = 0.3f;
        else if (it < 30000) cw = 0.6f;
        else                 cw = 1.0f;
        const float p0 = fmaxf(0.f, epsv - 0.8f);
        const float p1 = fmaxf(0.f, 0.2f - epsv);
        const float eps_bp = p0 * p0 + p1 * p1;
        out[0] = 0.1f * loss_u + cw * loss_pde + 0.01f * eps_bp;
        out[1] = loss_u;
        out[2] = loss_pde;
    }
}

extern "C" void kernel_launch(void* const* d_in, const int* in_sizes, int n_in,
                              void* d_out, int out_size, void* d_ws, size_t ws_size,
                              hipStream_t stream) {
    const float* x       = (const float*)d_in[0];
    const float* y       = (const float*)d_in[1];
    const float* u       = (const float*)d_in[2];
    const float* centers = (const float*)d_in[3];
    const float* W       = (const float*)d_in[4];
    const float* eps     = (const float*)d_in[5];
    const float* delta   = (const float*)d_in[6];
    const float* gam     = (const float*)d_in[7];
    const int*   iters   = (const int*)d_in[8];
    float* out = (float*)d_out;
    float* partial = (float*)d_ws;   // 3 * GRID floats = 6 KB

    void* args[] = {
        (void*)&x, (void*)&y, (void*)&u, (void*)&centers, (void*)&W,
        (void*)&eps, (void*)&delta, (void*)&gam, (void*)&iters,
        (void*)&partial, (void*)&out
    };
    hipLaunchCooperativeKernel((void*)rbf_pinn_coop, dim3(GRID), dim3(BLOCK),
                               args, 0, stream);
}

// Round 4
// 17.915 us; speedup vs baseline: 3.2889x; 3.2889x over previous
//
#include <hip/hip_runtime.h>
#include <math.h>

#define N_PTS 131072
#define UNITS 256
#define PAIRS (UNITS / 2)
#define BLOCK 256
#define GRID  (N_PTS / BLOCK)   // 512 blocks, one thread per point

// Closed form: phi = exp(-0.5*s), s = (x-cx)^2 + (y-cy)^2
//   u_pred = sum phi*w
//   sh     = u + 2*lap(u) + biharm(u) = sum phi*w*(s^2 - 6s + 5)
//
// c = -0.5*log2(e):  exp(-0.5*s) = exp2(c*s) = E0 * exp2(q),
//   E0 = exp2(c*(x^2+y^2)) per thread,
//   q  = A*x + B*y + D per (thread,center); A=-2c*cx, B=-2c*cy, D=c*(cx^2+cy^2).
// s = q/c + r0 (r0 = x^2+y^2):
//   s^2-6s+5 = alpha*q^2 + beta*q + gamma;
//   alpha = 1/c^2, beta = (2*r0-6)/c, gamma = r0^2-6*r0+5.
//
// Centers processed two per iteration; LDS stores pair-adjacent coefficients
// {A0,A1,B0,B1} and {D0,D1,w0,w1} so the paired FMAs can map to v_pk_fma_f32.

__global__ __launch_bounds__(BLOCK) void rbf_pinn_main(
    const float* __restrict__ x, const float* __restrict__ y,
    const float* __restrict__ u, const float* __restrict__ centers,
    const float* __restrict__ W, const float* __restrict__ eps,
    const float* __restrict__ delta, const float* __restrict__ gam,
    const int* __restrict__ iters, float* __restrict__ partial)
{
    constexpr double LOG2E = 1.4426950408889634073599;
    constexpr float  cF    = (float)(-0.5 * LOG2E);
    constexpr float  alpha = (float)(1.0 / (0.25 * LOG2E * LOG2E));  // 1/c^2
    constexpr float  m2c   = (float)(2.0 / (-0.5 * LOG2E));          // 2/c
    constexpr float  m6c   = (float)(-6.0 / (-0.5 * LOG2E));         // -6/c

    __shared__ float4 s_ab[PAIRS];   // {A_2p, A_2p+1, B_2p, B_2p+1}
    __shared__ float4 s_dw[PAIRS];   // {D_2p, D_2p+1, w_2p, w_2p+1}
    const int t = threadIdx.x;

    if (t < PAIRS) {
        const float cx0 = centers[4 * t + 0];
        const float cy0 = centers[4 * t + 1];
        const float cx1 = centers[4 * t + 2];
        const float cy1 = centers[4 * t + 3];
        const float w0  = W[2 * t + 0];
        const float w1  = W[2 * t + 1];
        s_ab[t] = make_float4(-2.f * cF * cx0, -2.f * cF * cx1,
                              -2.f * cF * cy0, -2.f * cF * cy1);
        s_dw[t] = make_float4(cF * fmaf(cx0, cx0, cy0 * cy0),
                              cF * fmaf(cx1, cx1, cy1 * cy1), w0, w1);
    }
    __syncthreads();

    const int i = blockIdx.x * BLOCK + t;
    const float xi = x[i];
    const float yi = y[i];
    const float ui = u[i];

    const float r0   = fmaf(xi, xi, yi * yi);
    const float E0   = __builtin_amdgcn_exp2f(cF * r0);
    const float beta = fmaf(m2c, r0, m6c);
    const float gmma = fmaf(r0, r0 - 6.f, 5.f);

    // Paired accumulators (lane-local float2 halves -> pk ops).
    float up0 = 0.f, up1 = 0.f;
    float sh0 = 0.f, sh1 = 0.f;

    #pragma unroll 4
    for (int p = 0; p < PAIRS; ++p) {
        const float4 ab = s_ab[p];   // ds_read_b128 broadcast
        const float4 dw = s_dw[p];   // ds_read_b128 broadcast
        const float q0 = fmaf(ab.x, xi, fmaf(ab.z, yi, dw.x));
        const float q1 = fmaf(ab.y, xi, fmaf(ab.w, yi, dw.y));
        const float e0 = __builtin_amdgcn_exp2f(q0);
        const float e1 = __builtin_amdgcn_exp2f(q1);
        const float p10 = fmaf(alpha, q0, beta);
        const float p11 = fmaf(alpha, q1, beta);
        const float pl0 = fmaf(q0, p10, gmma);
        const float pl1 = fmaf(q1, p11, gmma);
        const float ew0 = e0 * dw.z;
        const float ew1 = e1 * dw.w;
        up0 += ew0;
        up1 += ew1;
        sh0 = fmaf(ew0, pl0, sh0);
        sh1 = fmaf(ew1, pl1, sh1);
    }
    const float up = (up0 + up1) * E0;
    const float sh = (sh0 + sh1) * E0;

    const int   it   = iters[0];
    const float epsv = eps[0];
    const float dl   = delta[0];
    const float gm   = gam[0];
    float c2, c3;
    if (it < 10000)      { c2 = 0.0f; c3 = 0.0f; }
    else if (it < 20000) { c2 = 0.3f; c3 = 0.0f; }
    else if (it < 30000) { c2 = 0.7f; c3 = 0.3f; }
    else                 { c2 = 1.0f; c3 = 1.0f; }

    const float up2 = up * up;
    const float res = epsv * up - c2 * dl * up2 - c3 * gm * up2 * up - sh;
    const float d   = up - ui;

    float a0 = d * d;
    float a1 = ui * ui;
    float a2 = res * res;

    #pragma unroll
    for (int o = 32; o > 0; o >>= 1) {
        a0 += __shfl_down(a0, o);
        a1 += __shfl_down(a1, o);
        a2 += __shfl_down(a2, o);
    }
    __shared__ float s_r[3][BLOCK / 64];
    const int lane = t & 63;
    const int wv   = t >> 6;
    if (lane == 0) { s_r[0][wv] = a0; s_r[1][wv] = a1; s_r[2][wv] = a2; }
    __syncthreads();
    if (t == 0) {
        float r0s = 0.f, r1s = 0.f, r2s = 0.f;
        #pragma unroll
        for (int w2 = 0; w2 < BLOCK / 64; ++w2) {
            r0s += s_r[0][w2]; r1s += s_r[1][w2]; r2s += s_r[2][w2];
        }
        partial[0 * GRID + blockIdx.x] = r0s;
        partial[1 * GRID + blockIdx.x] = r1s;
        partial[2 * GRID + blockIdx.x] = r2s;
    }
}

__global__ __launch_bounds__(256) void rbf_pinn_final(
    const float* __restrict__ partial, const float* __restrict__ eps,
    const int* __restrict__ iters, float* __restrict__ out)
{
    const int t = threadIdx.x;
    float a0 = 0.f, a1 = 0.f, a2 = 0.f;
    #pragma unroll
    for (int k = t; k < GRID; k += 256) {
        a0 += partial[0 * GRID + k];
        a1 += partial[1 * GRID + k];
        a2 += partial[2 * GRID + k];
    }
    #pragma unroll
    for (int o = 32; o > 0; o >>= 1) {
        a0 += __shfl_down(a0, o);
        a1 += __shfl_down(a1, o);
        a2 += __shfl_down(a2, o);
    }
    __shared__ float s_r[3][4];
    const int lane = t & 63;
    const int wv   = t >> 6;
    if (lane == 0) { s_r[0][wv] = a0; s_r[1][wv] = a1; s_r[2][wv] = a2; }
    __syncthreads();
    if (t == 0) {
        float S0 = 0.f, S1 = 0.f, S2 = 0.f;
        #pragma unroll
        for (int w2 = 0; w2 < 4; ++w2) { S0 += s_r[0][w2]; S1 += s_r[1][w2]; S2 += s_r[2][w2]; }
        const float loss_u   = S0 / S1;
        const float loss_pde = S2 / (float)N_PTS;
        const int it = iters[0];
        float cw;
        if (it < 10000)      cw = 0.1f;
        else if (it < 20000) cw = 0.3f;
        else if (it < 30000) cw = 0.6f;
        else                 cw = 1.0f;
        const float e  = eps[0];
        const float p0 = fmaxf(0.f, e - 0.8f);
        const float p1 = fmaxf(0.f, 0.2f - e);
        const float eps_bp = p0 * p0 + p1 * p1;
        out[0] = 0.1f * loss_u + cw * loss_pde + 0.01f * eps_bp;
        out[1] = loss_u;
        out[2] = loss_pde;
    }
}

extern "C" void kernel_launch(void* const* d_in, const int* in_sizes, int n_in,
                              void* d_out, int out_size, void* d_ws, size_t ws_size,
                              hipStream_t stream) {
    const float* x       = (const float*)d_in[0];
    const float* y       = (const float*)d_in[1];
    const float* u       = (const float*)d_in[2];
    const float* centers = (const float*)d_in[3];
    const float* W       = (const float*)d_in[4];
    const float* eps     = (const float*)d_in[5];
    const float* delta   = (const float*)d_in[6];
    const float* gam     = (const float*)d_in[7];
    const int*   iters   = (const int*)d_in[8];
    float* out = (float*)d_out;
    float* partial = (float*)d_ws;   // 3 * GRID floats = 6 KB

    rbf_pinn_main<<<GRID, BLOCK, 0, stream>>>(x, y, u, centers, W, eps, delta,
                                              gam, iters, partial);
    rbf_pinn_final<<<1, 256, 0, stream>>>(partial, eps, iters, out);
}

// Round 5
// 17.836 us; speedup vs baseline: 3.3035x; 1.0045x over previous
//
#include <hip/hip_runtime.h>
#include <math.h>

#define N_PTS 131072
#define UNITS 256
#define PAIRS (UNITS / 2)
#define BLOCK 256
#define GRID  (N_PTS / BLOCK)   // 512 blocks, one thread per point

typedef float f32x2 __attribute__((ext_vector_type(2)));

#if defined(__has_builtin)
#  if __has_builtin(__builtin_elementwise_fma)
#    define PK_FMA(a, b, c) __builtin_elementwise_fma((a), (b), (c))
#  endif
#endif
#ifndef PK_FMA
static __device__ __forceinline__ f32x2 pk_fma_fallback(f32x2 a, f32x2 b, f32x2 c) {
    f32x2 r; r.x = fmaf(a.x, b.x, c.x); r.y = fmaf(a.y, b.y, c.y); return r;
}
#  define PK_FMA(a, b, c) pk_fma_fallback((a), (b), (c))
#endif

// Closed form: phi = exp(-0.5*s), s = (x-cx)^2 + (y-cy)^2
//   u_pred = sum phi*w
//   sh     = u + 2*lap(u) + biharm(u) = sum phi*w*(s^2 - 6s + 5)
// c = -0.5*log2(e):  exp(-0.5*s) = E0 * exp2(q),
//   E0 = exp2(c*(x^2+y^2)); q = A*x + B*y + D per center
//   A=-2c*cx, B=-2c*cy, D=c*(cx^2+cy^2)
// s = q/c + r0 (r0 = x^2+y^2):
//   s^2-6s+5 = alpha*q^2 + beta*q + gamma
//   alpha = 1/c^2, beta = (2*r0-6)/c, gamma = r0^2-6*r0+5
// Two centers per iteration, all pair math in f32x2 -> v_pk_* VOP3P ops.

__global__ __launch_bounds__(BLOCK) void rbf_pinn_main(
    const float* __restrict__ x, const float* __restrict__ y,
    const float* __restrict__ u, const float* __restrict__ centers,
    const float* __restrict__ W, const float* __restrict__ eps,
    const float* __restrict__ delta, const float* __restrict__ gam,
    const int* __restrict__ iters, float* __restrict__ partial)
{
    constexpr double LOG2E = 1.4426950408889634073599;
    constexpr float  cF    = (float)(-0.5 * LOG2E);
    constexpr float  alpha = (float)(1.0 / (0.25 * LOG2E * LOG2E));  // 1/c^2
    constexpr float  m2c   = (float)(2.0 / (-0.5 * LOG2E));          // 2/c
    constexpr float  m6c   = (float)(-6.0 / (-0.5 * LOG2E));         // -6/c

    __shared__ float4 s_ab[PAIRS];   // {A_2p, A_2p+1, B_2p, B_2p+1}
    __shared__ float4 s_dw[PAIRS];   // {D_2p, D_2p+1, w_2p, w_2p+1}
    const int t = threadIdx.x;

    if (t < PAIRS) {
        const float cx0 = centers[4 * t + 0];
        const float cy0 = centers[4 * t + 1];
        const float cx1 = centers[4 * t + 2];
        const float cy1 = centers[4 * t + 3];
        const float w0  = W[2 * t + 0];
        const float w1  = W[2 * t + 1];
        s_ab[t] = make_float4(-2.f * cF * cx0, -2.f * cF * cx1,
                              -2.f * cF * cy0, -2.f * cF * cy1);
        s_dw[t] = make_float4(cF * fmaf(cx0, cx0, cy0 * cy0),
                              cF * fmaf(cx1, cx1, cy1 * cy1), w0, w1);
    }
    __syncthreads();

    const int i = blockIdx.x * BLOCK + t;
    const float xi = x[i];
    const float yi = y[i];
    const float ui = u[i];

    const float r0   = fmaf(xi, xi, yi * yi);
    const float E0   = __builtin_amdgcn_exp2f(cF * r0);
    const f32x2 x2   = { xi, xi };
    const f32x2 y2   = { yi, yi };
    const f32x2 al2  = { alpha, alpha };
    const f32x2 be2  = { fmaf(m2c, r0, m6c), fmaf(m2c, r0, m6c) };
    const f32x2 ga2  = { fmaf(r0, r0 - 6.f, 5.f), fmaf(r0, r0 - 6.f, 5.f) };

    f32x2 up = { 0.f, 0.f };
    f32x2 sh = { 0.f, 0.f };

    #pragma unroll 4
    for (int p = 0; p < PAIRS; ++p) {
        const float4 ab4 = s_ab[p];               // ds_read_b128 broadcast
        const float4 dw4 = s_dw[p];               // ds_read_b128 broadcast
        const f32x2 A = { ab4.x, ab4.y };
        const f32x2 B = { ab4.z, ab4.w };
        const f32x2 D = { dw4.x, dw4.y };
        const f32x2 w = { dw4.z, dw4.w };
        const f32x2 q = PK_FMA(A, x2, PK_FMA(B, y2, D));
        f32x2 e;
        e.x = __builtin_amdgcn_exp2f(q.x);
        e.y = __builtin_amdgcn_exp2f(q.y);
        const f32x2 p1   = PK_FMA(al2, q, be2);
        const f32x2 poly = PK_FMA(q, p1, ga2);
        const f32x2 ew   = e * w;
        up += ew;
        sh = PK_FMA(ew, poly, sh);
    }
    const float upf = (up.x + up.y) * E0;
    const float shf = (sh.x + sh.y) * E0;

    const int   it   = iters[0];
    const float epsv = eps[0];
    const float dl   = delta[0];
    const float gm   = gam[0];
    float c2, c3;
    if (it < 10000)      { c2 = 0.0f; c3 = 0.0f; }
    else if (it < 20000) { c2 = 0.3f; c3 = 0.0f; }
    else if (it < 30000) { c2 = 0.7f; c3 = 0.3f; }
    else                 { c2 = 1.0f; c3 = 1.0f; }

    const float up2 = upf * upf;
    const float res = epsv * upf - c2 * dl * up2 - c3 * gm * up2 * upf - shf;
    const float d   = upf - ui;

    float a0 = d * d;
    float a1 = ui * ui;
    float a2 = res * res;

    #pragma unroll
    for (int o = 32; o > 0; o >>= 1) {
        a0 += __shfl_down(a0, o);
        a1 += __shfl_down(a1, o);
        a2 += __shfl_down(a2, o);
    }
    __shared__ float s_r[3][BLOCK / 64];
    const int lane = t & 63;
    const int wv   = t >> 6;
    if (lane == 0) { s_r[0][wv] = a0; s_r[1][wv] = a1; s_r[2][wv] = a2; }
    __syncthreads();
    if (t == 0) {
        float r0s = 0.f, r1s = 0.f, r2s = 0.f;
        #pragma unroll
        for (int w2 = 0; w2 < BLOCK / 64; ++w2) {
            r0s += s_r[0][w2]; r1s += s_r[1][w2]; r2s += s_r[2][w2];
        }
        partial[0 * GRID + blockIdx.x] = r0s;
        partial[1 * GRID + blockIdx.x] = r1s;
        partial[2 * GRID + blockIdx.x] = r2s;
    }
}

// Single-wave final reduction: no LDS, no __syncthreads.
__global__ __launch_bounds__(64) void rbf_pinn_final(
    const float* __restrict__ partial, const float* __restrict__ eps,
    const int* __restrict__ iters, float* __restrict__ out)
{
    const int t = threadIdx.x;
    float a0 = 0.f, a1 = 0.f, a2 = 0.f;
    #pragma unroll
    for (int k = t; k < GRID; k += 64) {
        a0 += partial[0 * GRID + k];
        a1 += partial[1 * GRID + k];
        a2 += partial[2 * GRID + k];
    }
    #pragma unroll
    for (int o = 32; o > 0; o >>= 1) {
        a0 += __shfl_down(a0, o);
        a1 += __shfl_down(a1, o);
        a2 += __shfl_down(a2, o);
    }
    if (t == 0) {
        const float loss_u   = a0 / a1;
        const float loss_pde = a2 / (float)N_PTS;
        const int it = iters[0];
        float cw;
        if (it < 10000)      cw = 0.1f;
        else if (it < 20000) cw = 0.3f;
        else if (it < 30000) cw = 0.6f;
        else                 cw = 1.0f;
        const float e  = eps[0];
        const float p0 = fmaxf(0.f, e - 0.8f);
        const float p1 = fmaxf(0.f, 0.2f - e);
        const float eps_bp = p0 * p0 + p1 * p1;
        out[0] = 0.1f * loss_u + cw * loss_pde + 0.01f * eps_bp;
        out[1] = loss_u;
        out[2] = loss_pde;
    }
}

extern "C" void kernel_launch(void* const* d_in, const int* in_sizes, int n_in,
                              void* d_out, int out_size, void* d_ws, size_t ws_size,
                              hipStream_t stream) {
    const float* x       = (const float*)d_in[0];
    const float* y       = (const float*)d_in[1];
    const float* u       = (const float*)d_in[2];
    const float* centers = (const float*)d_in[3];
    const float* W       = (const float*)d_in[4];
    const float* eps     = (const float*)d_in[5];
    const float* delta   = (const float*)d_in[6];
    const float* gam     = (const float*)d_in[7];
    const int*   iters   = (const int*)d_in[8];
    float* out = (float*)d_out;
    float* partial = (float*)d_ws;   // 3 * GRID floats = 6 KB

    rbf_pinn_main<<<GRID, BLOCK, 0, stream>>>(x, y, u, centers, W, eps, delta,
                                              gam, iters, partial);
    rbf_pinn_final<<<1, 64, 0, stream>>>(partial, eps, iters, out);
}